// Round 10
// baseline (227.330 us; speedup 1.0000x reference)
//
#include <hip/hip_runtime.h>
#include <hip/hip_fp16.h>
#include <type_traits>

#define NBUCK 512   // dst-range buckets; R = ceil(N/NBUCK) must be <= 256
#define CH    2048  // edges per scatter/hist block

typedef _Float16 half8 __attribute__((ext_vector_type(8)));
typedef float floatx4 __attribute__((ext_vector_type(4)));

__device__ inline void unpack8(const float4& raw, float* f) {
    const __half2* p = (const __half2*)&raw;
#pragma unroll
    for (int i = 0; i < 4; ++i) {
        float2 t = __half22float2(p[i]);
        f[2 * i] = t.x;
        f[2 * i + 1] = t.y;
    }
}

// ---------------- gemm1 body: X(M x 64) fp32 @ W1(64 x 64) -> fp16 ----------------

__device__ inline void gemm64_f32_body(const float* __restrict__ X, const float* __restrict__ W,
                                       __half* __restrict__ H, int M, int ntiles, int vblk,
                                       int GB) {
    constexpr int NC = 4;
    const int lane = threadIdx.x & 63;
    const int wid  = threadIdx.x >> 6;
    const int q    = lane >> 4;
    const int m    = lane & 15;

    half8 bfrag[2][NC];
#pragma unroll
    for (int s = 0; s < 2; ++s)
#pragma unroll
        for (int c = 0; c < NC; ++c)
#pragma unroll
            for (int j = 0; j < 8; ++j)
                bfrag[s][c][j] = (_Float16)W[(s * 32 + q * 8 + j) * 64 + c * 16 + m];

    for (int tile = vblk * 4 + wid; tile < ntiles; tile += GB * 4) {
        int rowBase = tile * 16;
        int rowA = rowBase + m;
        if (rowA > M - 1) rowA = M - 1;

        half8 afrag[2];
        const float4* Xr = (const float4*)(X + (size_t)rowA * 64);
#pragma unroll
        for (int s = 0; s < 2; ++s) {
            float4 v0 = Xr[s * 8 + q * 2 + 0];
            float4 v1 = Xr[s * 8 + q * 2 + 1];
            afrag[s][0] = (_Float16)v0.x;
            afrag[s][1] = (_Float16)v0.y;
            afrag[s][2] = (_Float16)v0.z;
            afrag[s][3] = (_Float16)v0.w;
            afrag[s][4] = (_Float16)v1.x;
            afrag[s][5] = (_Float16)v1.y;
            afrag[s][6] = (_Float16)v1.z;
            afrag[s][7] = (_Float16)v1.w;
        }

        floatx4 acc[NC];
#pragma unroll
        for (int c = 0; c < NC; ++c) acc[c] = (floatx4){0.f, 0.f, 0.f, 0.f};
#pragma unroll
        for (int s = 0; s < 2; ++s)
#pragma unroll
            for (int c = 0; c < NC; ++c)
                acc[c] = __builtin_amdgcn_mfma_f32_16x16x32_f16(afrag[s], bfrag[s][c], acc[c],
                                                                0, 0, 0);

#pragma unroll
        for (int r = 0; r < 4; ++r) {
            int row = rowBase + q * 4 + r;
            if (row < M) {
#pragma unroll
                for (int c = 0; c < NC; ++c)
                    H[(size_t)row * 64 + c * 16 + m] = __float2half(acc[c][r]);
            }
        }
    }
}

// ---------------- K1: per-block dst histogram (rows, no init/atomics) + gemm1 fused ----------------

__global__ __launch_bounds__(256) void hist_gemm1_kernel(
    const int* __restrict__ dst, int* __restrict__ blockHist,
    const float* __restrict__ X, const float* __restrict__ W1, __half* __restrict__ H,
    int M, int ntiles, int E, int R, int HB, int GB) {
    int blk = blockIdx.x;
    if (blk < HB) {
        __shared__ int h[NBUCK];
        int tid = threadIdx.x;
        for (int i = tid; i < NBUCK; i += 256) h[i] = 0;
        __syncthreads();
        int start = blk * CH;
        int count = E - start;
        if (count > CH) count = CH;
        for (int i = tid; i < count; i += 256) atomicAdd(&h[dst[start + i] / R], 1);
        __syncthreads();
        for (int i = tid; i < NBUCK; i += 256) blockHist[(size_t)blk * NBUCK + i] = h[i];
    } else {
        gemm64_f32_body(X, W1, H, M, ntiles, blk - HB, GB);
    }
}

// ---------------- K2: per-bucket serial scan over blocks + block scan of bucket totals ----------

__global__ __launch_bounds__(NBUCK) void scan_bases_kernel(const int* __restrict__ blockHist,
                                                           int* __restrict__ baseTbl,
                                                           int* __restrict__ bucketStart, int HB) {
    __shared__ int lds[NBUCK];
    int b = threadIdx.x;  // thread owns bucket b
    int running = 0;
    int k = 0;
    for (; k + 8 <= HB; k += 8) {
        int v[8];
#pragma unroll
        for (int u = 0; u < 8; ++u) v[u] = blockHist[(size_t)(k + u) * NBUCK + b];
#pragma unroll
        for (int u = 0; u < 8; ++u) {
            baseTbl[(size_t)(k + u) * NBUCK + b] = running;
            running += v[u];
        }
    }
    for (; k < HB; ++k) {
        int v = blockHist[(size_t)k * NBUCK + b];
        baseTbl[(size_t)k * NBUCK + b] = running;
        running += v;
    }
    lds[b] = running;
    __syncthreads();
    for (int off = 1; off < NBUCK; off <<= 1) {
        int x = (b >= off) ? lds[b - off] : 0;
        __syncthreads();
        lds[b] += x;
        __syncthreads();
    }
    bucketStart[b] = lds[b] - running;  // exclusive
    if (b == NBUCK - 1) bucketStart[NBUCK] = lds[b];
}

// ---------------- K3: single-pass scatter into bucket regions (no global atomics) ----------------

__global__ __launch_bounds__(256) void scatter_kernel(
    const int* __restrict__ src, const int* __restrict__ dst, const int* __restrict__ baseTbl,
    const int* __restrict__ bucketStart, unsigned long long* __restrict__ pairs, int E, int R) {
    __shared__ int lcur[NBUCK];
    int blk = blockIdx.x, tid = threadIdx.x;
    for (int i = tid; i < NBUCK; i += 256)
        lcur[i] = bucketStart[i] + baseTbl[(size_t)blk * NBUCK + i];
    __syncthreads();
    int start = blk * CH;
    int count = E - start;
    if (count > CH) count = CH;
    for (int i = tid; i < count; i += 256) {
        int d = dst[start + i];
        int s = src[start + i];
        int b = d / R;
        int r = atomicAdd(&lcur[b], 1);
        pairs[r] = ((unsigned long long)(unsigned)s << 32) | (unsigned)d;
    }
}

// ---------------- K4: per-bucket CSR build, pairs staged in LDS (single global read) ----------------

__global__ __launch_bounds__(256) void bucket_csr_kernel(
    const unsigned long long* __restrict__ pairs, const int* __restrict__ bucketStart,
    int* __restrict__ counts, int* __restrict__ offs, float* __restrict__ dinv,
    int* __restrict__ ssrc, int N, int R) {
    __shared__ unsigned long long stage[3072];
    __shared__ int h[256];
    __shared__ int loffs[256];
    __shared__ int cur[256];
    int b = blockIdx.x, tid = threadIdx.x;
    int nodeBase = b * R;
    int beg = bucketStart[b], end = bucketStart[b + 1];
    int len = end - beg;
    int sl = len < 3072 ? len : 3072;
    for (int i = tid; i < sl; i += 256) stage[i] = pairs[beg + i];
    h[tid] = 0;
    __syncthreads();
    for (int i = tid; i < len; i += 256) {
        unsigned long long p = (i < 3072) ? stage[i] : pairs[beg + i];
        atomicAdd(&h[(int)(p & 0xffffffffull) - nodeBase], 1);
    }
    __syncthreads();
    int v = h[tid];
    loffs[tid] = v;
    __syncthreads();
    for (int off = 1; off < 256; off <<= 1) {
        int x = (tid >= off) ? loffs[tid - off] : 0;
        __syncthreads();
        loffs[tid] += x;
        __syncthreads();
    }
    int excl = loffs[tid] - v;
    cur[tid] = excl;
    int node = nodeBase + tid;
    if (tid < R && node < N) {
        counts[node] = v;
        offs[node] = beg + excl;
        dinv[node] = rsqrtf((float)v + 1.0f);  // +1 self-loop
    }
    __syncthreads();
    for (int i = tid; i < len; i += 256) {
        unsigned long long p = (i < 3072) ? stage[i] : pairs[beg + i];
        int d = (int)(p & 0xffffffffull) - nodeBase;
        int s = (int)(p >> 32);
        int r = atomicAdd(&cur[d], 1);
        ssrc[beg + r] = s;
    }
}

// ---------------- gemm2: out1(M x 64) fp16 @ W2(64 x 32) -> fp16 ----------------

__global__ __launch_bounds__(256) void gemm2_mfma_kernel(const __half* __restrict__ X,
                                                         const float* __restrict__ W,
                                                         __half* __restrict__ H, int M,
                                                         int ntiles) {
    constexpr int NC = 2;
    const int lane = threadIdx.x & 63;
    const int wid  = threadIdx.x >> 6;
    const int q    = lane >> 4;
    const int m    = lane & 15;

    half8 bfrag[2][NC];
#pragma unroll
    for (int s = 0; s < 2; ++s)
#pragma unroll
        for (int c = 0; c < NC; ++c)
#pragma unroll
            for (int j = 0; j < 8; ++j)
                bfrag[s][c][j] = (_Float16)W[(s * 32 + q * 8 + j) * 32 + c * 16 + m];

    for (int tile = blockIdx.x * 4 + wid; tile < ntiles; tile += gridDim.x * 4) {
        int rowBase = tile * 16;
        int rowA = rowBase + m;
        if (rowA > M - 1) rowA = M - 1;

        const half8* Xr = (const half8*)(X + (size_t)rowA * 64);
        half8 afrag[2];
#pragma unroll
        for (int s = 0; s < 2; ++s) afrag[s] = Xr[s * 4 + q];

        floatx4 acc[NC];
#pragma unroll
        for (int c = 0; c < NC; ++c) acc[c] = (floatx4){0.f, 0.f, 0.f, 0.f};
#pragma unroll
        for (int s = 0; s < 2; ++s)
#pragma unroll
            for (int c = 0; c < NC; ++c)
                acc[c] = __builtin_amdgcn_mfma_f32_16x16x32_f16(afrag[s], bfrag[s][c], acc[c],
                                                                0, 0, 0);

#pragma unroll
        for (int r = 0; r < 4; ++r) {
            int row = rowBase + q * 4 + r;
            if (row < M) {
#pragma unroll
                for (int c = 0; c < NC; ++c)
                    H[(size_t)row * 32 + c * 16 + m] = __float2half(acc[c][r]);
            }
        }
    }
}

// ---------------- agg64: 8-lane group per node, no cross-lane reduction ----------------

__global__ __launch_bounds__(256) void agg64_kernel(
    const float4* __restrict__ hrow4, const int* __restrict__ ssrc,
    const int* __restrict__ offs, const int* __restrict__ counts,
    const float* __restrict__ dinv, const float* __restrict__ b1,
    float4* __restrict__ out4, int N) {
    int tid  = threadIdx.x;
    int lane = tid & 63;
    int l    = tid & 7;            // lane within group
    int gb   = lane & 56;          // group base lane within wave
    int node = blockIdx.x * 32 + (tid >> 3);
    if (node >= N) return;
    int beg = offs[node], cnt = counts[node];
    float a[8];
#pragma unroll
    for (int j = 0; j < 8; ++j) a[j] = 0.f;
    for (int base = 0; base < cnt; base += 8) {
        int p = base + l;
        int idx = 0;
        float dv = 0.0f;
        if (p < cnt) {
            idx = ssrc[beg + p];
            dv  = dinv[idx];
        }
#pragma unroll
        for (int j = 0; j < 8; ++j) {
            int   s  = __shfl(idx, gb | j, 64);
            float nv = __shfl(dv, gb | j, 64);
            float4 raw = hrow4[(size_t)s * 8 + l];
            float f[8];
            unpack8(raw, f);
#pragma unroll
            for (int d = 0; d < 8; ++d) a[d] = fmaf(f[d], nv, a[d]);
        }
    }
    float dd = dinv[node];
    float4 sraw = hrow4[(size_t)node * 8 + l];
    float sf[8];
    unpack8(sraw, sf);
    __half2 pk[4];
#pragma unroll
    for (int i = 0; i < 4; ++i) {
        float rx = fmaxf(dd * (a[2 * i] + sf[2 * i] * dd) + b1[8 * l + 2 * i], 0.0f);
        float ry = fmaxf(dd * (a[2 * i + 1] + sf[2 * i + 1] * dd) + b1[8 * l + 2 * i + 1], 0.0f);
        pk[i] = __floats2half2_rn(rx, ry);
    }
    out4[(size_t)node * 8 + l] = *(const float4*)pk;
}

// ---------------- agg32: 4-lane group per node -> fp32 out ----------------

__global__ __launch_bounds__(256) void agg32_kernel(
    const float4* __restrict__ hrow4, const int* __restrict__ ssrc,
    const int* __restrict__ offs, const int* __restrict__ counts,
    const float* __restrict__ dinv, const float* __restrict__ b2,
    float4* __restrict__ out4, int N) {
    int tid  = threadIdx.x;
    int lane = tid & 63;
    int l    = tid & 3;            // lane within group
    int gb   = lane & 60;          // group base lane within wave
    int node = blockIdx.x * 64 + (tid >> 2);
    if (node >= N) return;
    int beg = offs[node], cnt = counts[node];
    float a[8];
#pragma unroll
    for (int j = 0; j < 8; ++j) a[j] = 0.f;
    for (int base = 0; base < cnt; base += 4) {
        int p = base + l;
        int idx = 0;
        float dv = 0.0f;
        if (p < cnt) {
            idx = ssrc[beg + p];
            dv  = dinv[idx];
        }
#pragma unroll
        for (int j = 0; j < 4; ++j) {
            int   s  = __shfl(idx, gb | j, 64);
            float nv = __shfl(dv, gb | j, 64);
            float4 raw = hrow4[(size_t)s * 4 + l];
            float f[8];
            unpack8(raw, f);
#pragma unroll
            for (int d = 0; d < 8; ++d) a[d] = fmaf(f[d], nv, a[d]);
        }
    }
    float dd = dinv[node];
    float4 sraw = hrow4[(size_t)node * 4 + l];
    float sf[8];
    unpack8(sraw, sf);
    float r[8];
#pragma unroll
    for (int j = 0; j < 8; ++j)
        r[j] = dd * (a[j] + sf[j] * dd) + b2[8 * l + j];
    out4[(size_t)node * 8 + 2 * l + 0] = make_float4(r[0], r[1], r[2], r[3]);
    out4[(size_t)node * 8 + 2 * l + 1] = make_float4(r[4], r[5], r[6], r[7]);
}

// ---------------- launch ----------------

extern "C" void kernel_launch(void* const* d_in, const int* in_sizes, int n_in,
                              void* d_out, int out_size, void* d_ws, size_t ws_size,
                              hipStream_t stream) {
    const float* x  = (const float*)d_in[0];
    const int*   ei = (const int*)d_in[1];
    const float* W1 = (const float*)d_in[2];
    const float* b1 = (const float*)d_in[3];
    const float* W2 = (const float*)d_in[4];
    const float* b2 = (const float*)d_in[5];
    float* out = (float*)d_out;

    const int N = in_sizes[0] / 64;   // 100000
    const int E = in_sizes[1] / 2;    // 1200000
    const int* src = ei;
    const int* dst = ei + E;

    const int Npad = (N + 1023) & ~1023;      // 100352
    const int R    = (N + NBUCK - 1) / NBUCK; // 196 (<= 256)
    const int HB   = (E + CH - 1) / CH;       // 586
    const int GB   = 782;

    // workspace layout
    unsigned long long* pairs = (unsigned long long*)d_ws;        // E
    int*   ssrc        = (int*)(pairs + E);                       // E
    int*   counts      = ssrc + E;                                // Npad
    int*   offs        = counts + Npad;                           // Npad
    float* dinv        = (float*)(offs + Npad);                   // Npad
    int*   bucketStart = (int*)(dinv + Npad);                     // NBUCK+1
    int*   blockHist   = bucketStart + NBUCK + 2;                 // HB*NBUCK
    int*   baseTbl     = blockHist + (size_t)HB * NBUCK;          // HB*NBUCK
    size_t hoff = (size_t)(baseTbl + (size_t)HB * NBUCK - (int*)d_ws);
    hoff = (hoff + 3) & ~(size_t)3;                               // 16B align
    __half* h    = (__half*)((int*)d_ws + hoff);                  // N*64 fp16
    __half* out1 = h + (size_t)N * 64;                            // N*64 fp16
    __half* h2   = h;                                             // N*32 fp16, reuses h

    const int ntiles = (N + 15) / 16;  // 6250

    // K1: dst block-histogram + layer-1 GEMM (independent, fused dispatch)
    hist_gemm1_kernel<<<HB + GB, 256, 0, stream>>>(dst, blockHist, x, W1, h, N, ntiles,
                                                   E, R, HB, GB);
    // K2: bases
    scan_bases_kernel<<<1, NBUCK, 0, stream>>>(blockHist, baseTbl, bucketStart, HB);
    // K3: single-pass scatter into bucket regions
    scatter_kernel<<<HB, 256, 0, stream>>>(src, dst, baseTbl, bucketStart, pairs, E, R);
    // K4: per-bucket CSR build (LDS-staged)
    bucket_csr_kernel<<<NBUCK, 256, 0, stream>>>(pairs, bucketStart, counts, offs, dinv, ssrc,
                                                 N, R);
    // K5: layer-1 aggregation + relu
    agg64_kernel<<<(N + 31) / 32, 256, 0, stream>>>((const float4*)h, ssrc, offs, counts, dinv,
                                                    b1, (float4*)out1, N);
    // K6: layer-2 GEMM
    gemm2_mfma_kernel<<<782, 256, 0, stream>>>(out1, W2, h2, N, ntiles);
    // K7: layer-2 aggregation -> out
    agg32_kernel<<<(N + 63) / 64, 256, 0, stream>>>((const float4*)h2, ssrc, offs, counts, dinv,
                                                    b2, (float4*)out, N);
}

// Round 11
// 196.433 us; speedup vs baseline: 1.1573x; 1.1573x over previous
//
#include <hip/hip_runtime.h>
#include <hip/hip_fp16.h>
#include <type_traits>

#define NBUCK 512   // dst-range buckets; R = ceil(N/NBUCK) must be <= 256
#define CH    4096  // edges per scatter/hist block (HB = ceil(E/CH) must be <= 512)

typedef _Float16 half8 __attribute__((ext_vector_type(8)));
typedef float floatx4 __attribute__((ext_vector_type(4)));

__device__ inline void unpack8(const float4& raw, float* f) {
    const __half2* p = (const __half2*)&raw;
#pragma unroll
    for (int i = 0; i < 4; ++i) {
        float2 t = __half22float2(p[i]);
        f[2 * i] = t.x;
        f[2 * i + 1] = t.y;
    }
}

// ---------------- gemm1 body: X(M x 64) fp32 @ W1(64 x 64) -> fp16 ----------------

__device__ inline void gemm64_f32_body(const float* __restrict__ X, const float* __restrict__ W,
                                       __half* __restrict__ H, int M, int ntiles, int vblk,
                                       int GB) {
    constexpr int NC = 4;
    const int lane = threadIdx.x & 63;
    const int wid  = threadIdx.x >> 6;
    const int q    = lane >> 4;
    const int m    = lane & 15;

    half8 bfrag[2][NC];
#pragma unroll
    for (int s = 0; s < 2; ++s)
#pragma unroll
        for (int c = 0; c < NC; ++c)
#pragma unroll
            for (int j = 0; j < 8; ++j)
                bfrag[s][c][j] = (_Float16)W[(s * 32 + q * 8 + j) * 64 + c * 16 + m];

    for (int tile = vblk * 4 + wid; tile < ntiles; tile += GB * 4) {
        int rowBase = tile * 16;
        int rowA = rowBase + m;
        if (rowA > M - 1) rowA = M - 1;

        half8 afrag[2];
        const float4* Xr = (const float4*)(X + (size_t)rowA * 64);
#pragma unroll
        for (int s = 0; s < 2; ++s) {
            float4 v0 = Xr[s * 8 + q * 2 + 0];
            float4 v1 = Xr[s * 8 + q * 2 + 1];
            afrag[s][0] = (_Float16)v0.x;
            afrag[s][1] = (_Float16)v0.y;
            afrag[s][2] = (_Float16)v0.z;
            afrag[s][3] = (_Float16)v0.w;
            afrag[s][4] = (_Float16)v1.x;
            afrag[s][5] = (_Float16)v1.y;
            afrag[s][6] = (_Float16)v1.z;
            afrag[s][7] = (_Float16)v1.w;
        }

        floatx4 acc[NC];
#pragma unroll
        for (int c = 0; c < NC; ++c) acc[c] = (floatx4){0.f, 0.f, 0.f, 0.f};
#pragma unroll
        for (int s = 0; s < 2; ++s)
#pragma unroll
            for (int c = 0; c < NC; ++c)
                acc[c] = __builtin_amdgcn_mfma_f32_16x16x32_f16(afrag[s], bfrag[s][c], acc[c],
                                                                0, 0, 0);

#pragma unroll
        for (int r = 0; r < 4; ++r) {
            int row = rowBase + q * 4 + r;
            if (row < M) {
#pragma unroll
                for (int c = 0; c < NC; ++c)
                    H[(size_t)row * 64 + c * 16 + m] = __float2half(acc[c][r]);
            }
        }
    }
}

// ---------------- K1: per-block dst histogram (rows, no init/atomics) + gemm1 fused ----------------

__global__ __launch_bounds__(256) void hist_gemm1_kernel(
    const int* __restrict__ dst, int* __restrict__ blockHist,
    const float* __restrict__ X, const float* __restrict__ W1, __half* __restrict__ H,
    int M, int ntiles, int E, int R, int HB, int GB) {
    int blk = blockIdx.x;
    if (blk < HB) {
        __shared__ int h[NBUCK];
        int tid = threadIdx.x;
        for (int i = tid; i < NBUCK; i += 256) h[i] = 0;
        __syncthreads();
        int start = blk * CH;
        int count = E - start;
        if (count > CH) count = CH;
        for (int i = tid; i < count; i += 256) atomicAdd(&h[dst[start + i] / R], 1);
        __syncthreads();
        for (int i = tid; i < NBUCK; i += 256) blockHist[(size_t)blk * NBUCK + i] = h[i];
    } else {
        gemm64_f32_body(X, W1, H, M, ntiles, blk - HB, GB);
    }
}

// ---------------- K2a: per-bucket column scan, 512 blocks (block b owns bucket b) ------------
// baseTblT[b][k] = exclusive prefix over block-rows k of blockHist[k][b]; totals[b] = column sum.

__global__ __launch_bounds__(256) void scan_cols_kernel(const int* __restrict__ blockHist,
                                                        int* __restrict__ baseTblT,
                                                        int* __restrict__ totals,
                                                        int HB, int HBpad) {
    __shared__ int lds[256];
    int b = blockIdx.x;
    int t = threadIdx.x;
    int k0 = 2 * t, k1 = 2 * t + 1;
    int v0 = (k0 < HB) ? blockHist[(size_t)k0 * NBUCK + b] : 0;
    int v1 = (k1 < HB) ? blockHist[(size_t)k1 * NBUCK + b] : 0;
    int s = v0 + v1;
    lds[t] = s;
    __syncthreads();
    for (int off = 1; off < 256; off <<= 1) {
        int x = (t >= off) ? lds[t - off] : 0;
        __syncthreads();
        lds[t] += x;
        __syncthreads();
    }
    int excl = lds[t] - s;
    if (k0 < HB) baseTblT[(size_t)b * HBpad + k0] = excl;
    if (k1 < HB) baseTblT[(size_t)b * HBpad + k1] = excl + v0;
    if (t == 255) totals[b] = lds[255];
}

// ---------------- K2b: exclusive scan of 512 bucket totals ----------------

__global__ __launch_bounds__(NBUCK) void scan_totals_kernel(const int* __restrict__ totals,
                                                            int* __restrict__ bucketStart) {
    __shared__ int lds[NBUCK];
    int b = threadIdx.x;
    int v = totals[b];
    lds[b] = v;
    __syncthreads();
    for (int off = 1; off < NBUCK; off <<= 1) {
        int x = (b >= off) ? lds[b - off] : 0;
        __syncthreads();
        lds[b] += x;
        __syncthreads();
    }
    bucketStart[b] = lds[b] - v;
    if (b == NBUCK - 1) bucketStart[NBUCK] = lds[b];
}

// ---------------- K3: single-pass scatter into bucket regions (no global atomics) ----------------

__global__ __launch_bounds__(256) void scatter_kernel(
    const int* __restrict__ src, const int* __restrict__ dst, const int* __restrict__ baseTblT,
    const int* __restrict__ bucketStart, unsigned long long* __restrict__ pairs, int E, int R,
    int HBpad) {
    __shared__ int lcur[NBUCK];
    int blk = blockIdx.x, tid = threadIdx.x;
    for (int i = tid; i < NBUCK; i += 256)
        lcur[i] = bucketStart[i] + baseTblT[(size_t)i * HBpad + blk];
    __syncthreads();
    int start = blk * CH;
    int count = E - start;
    if (count > CH) count = CH;
    for (int i = tid; i < count; i += 256) {
        int d = dst[start + i];
        int s = src[start + i];
        int b = d / R;
        int r = atomicAdd(&lcur[b], 1);
        pairs[r] = ((unsigned long long)(unsigned)s << 32) | (unsigned)d;
    }
}

// ---------------- K4: per-bucket CSR build, pairs staged in LDS (single global read) ----------------

__global__ __launch_bounds__(256) void bucket_csr_kernel(
    const unsigned long long* __restrict__ pairs, const int* __restrict__ bucketStart,
    int* __restrict__ counts, int* __restrict__ offs, float* __restrict__ dinv,
    int* __restrict__ ssrc, int N, int R) {
    __shared__ unsigned long long stage[3072];
    __shared__ int h[256];
    __shared__ int loffs[256];
    __shared__ int cur[256];
    int b = blockIdx.x, tid = threadIdx.x;
    int nodeBase = b * R;
    int beg = bucketStart[b], end = bucketStart[b + 1];
    int len = end - beg;
    int sl = len < 3072 ? len : 3072;
    for (int i = tid; i < sl; i += 256) stage[i] = pairs[beg + i];
    h[tid] = 0;
    __syncthreads();
    for (int i = tid; i < len; i += 256) {
        unsigned long long p = (i < 3072) ? stage[i] : pairs[beg + i];
        atomicAdd(&h[(int)(p & 0xffffffffull) - nodeBase], 1);
    }
    __syncthreads();
    int v = h[tid];
    loffs[tid] = v;
    __syncthreads();
    for (int off = 1; off < 256; off <<= 1) {
        int x = (tid >= off) ? loffs[tid - off] : 0;
        __syncthreads();
        loffs[tid] += x;
        __syncthreads();
    }
    int excl = loffs[tid] - v;
    cur[tid] = excl;
    int node = nodeBase + tid;
    if (tid < R && node < N) {
        counts[node] = v;
        offs[node] = beg + excl;
        dinv[node] = rsqrtf((float)v + 1.0f);  // +1 self-loop
    }
    __syncthreads();
    for (int i = tid; i < len; i += 256) {
        unsigned long long p = (i < 3072) ? stage[i] : pairs[beg + i];
        int d = (int)(p & 0xffffffffull) - nodeBase;
        int s = (int)(p >> 32);
        int r = atomicAdd(&cur[d], 1);
        ssrc[beg + r] = s;
    }
}

// ---------------- gemm2: out1(M x 64) fp16 @ W2(64 x 32) -> fp16 ----------------

__global__ __launch_bounds__(256) void gemm2_mfma_kernel(const __half* __restrict__ X,
                                                         const float* __restrict__ W,
                                                         __half* __restrict__ H, int M,
                                                         int ntiles) {
    constexpr int NC = 2;
    const int lane = threadIdx.x & 63;
    const int wid  = threadIdx.x >> 6;
    const int q    = lane >> 4;
    const int m    = lane & 15;

    half8 bfrag[2][NC];
#pragma unroll
    for (int s = 0; s < 2; ++s)
#pragma unroll
        for (int c = 0; c < NC; ++c)
#pragma unroll
            for (int j = 0; j < 8; ++j)
                bfrag[s][c][j] = (_Float16)W[(s * 32 + q * 8 + j) * 32 + c * 16 + m];

    for (int tile = blockIdx.x * 4 + wid; tile < ntiles; tile += gridDim.x * 4) {
        int rowBase = tile * 16;
        int rowA = rowBase + m;
        if (rowA > M - 1) rowA = M - 1;

        const half8* Xr = (const half8*)(X + (size_t)rowA * 64);
        half8 afrag[2];
#pragma unroll
        for (int s = 0; s < 2; ++s) afrag[s] = Xr[s * 4 + q];

        floatx4 acc[NC];
#pragma unroll
        for (int c = 0; c < NC; ++c) acc[c] = (floatx4){0.f, 0.f, 0.f, 0.f};
#pragma unroll
        for (int s = 0; s < 2; ++s)
#pragma unroll
            for (int c = 0; c < NC; ++c)
                acc[c] = __builtin_amdgcn_mfma_f32_16x16x32_f16(afrag[s], bfrag[s][c], acc[c],
                                                                0, 0, 0);

#pragma unroll
        for (int r = 0; r < 4; ++r) {
            int row = rowBase + q * 4 + r;
            if (row < M) {
#pragma unroll
                for (int c = 0; c < NC; ++c)
                    H[(size_t)row * 32 + c * 16 + m] = __float2half(acc[c][r]);
            }
        }
    }
}

// ---------------- agg64: 8-lane group per node, no cross-lane reduction ----------------

__global__ __launch_bounds__(256) void agg64_kernel(
    const float4* __restrict__ hrow4, const int* __restrict__ ssrc,
    const int* __restrict__ offs, const int* __restrict__ counts,
    const float* __restrict__ dinv, const float* __restrict__ b1,
    float4* __restrict__ out4, int N) {
    int tid  = threadIdx.x;
    int lane = tid & 63;
    int l    = tid & 7;            // lane within group
    int gb   = lane & 56;          // group base lane within wave
    int node = blockIdx.x * 32 + (tid >> 3);
    if (node >= N) return;
    int beg = offs[node], cnt = counts[node];
    float a[8];
#pragma unroll
    for (int j = 0; j < 8; ++j) a[j] = 0.f;
    for (int base = 0; base < cnt; base += 8) {
        int p = base + l;
        int idx = 0;
        float dv = 0.0f;
        if (p < cnt) {
            idx = ssrc[beg + p];
            dv  = dinv[idx];
        }
#pragma unroll
        for (int j = 0; j < 8; ++j) {
            int   s  = __shfl(idx, gb | j, 64);
            float nv = __shfl(dv, gb | j, 64);
            float4 raw = hrow4[(size_t)s * 8 + l];
            float f[8];
            unpack8(raw, f);
#pragma unroll
            for (int d = 0; d < 8; ++d) a[d] = fmaf(f[d], nv, a[d]);
        }
    }
    float dd = dinv[node];
    float4 sraw = hrow4[(size_t)node * 8 + l];
    float sf[8];
    unpack8(sraw, sf);
    __half2 pk[4];
#pragma unroll
    for (int i = 0; i < 4; ++i) {
        float rx = fmaxf(dd * (a[2 * i] + sf[2 * i] * dd) + b1[8 * l + 2 * i], 0.0f);
        float ry = fmaxf(dd * (a[2 * i + 1] + sf[2 * i + 1] * dd) + b1[8 * l + 2 * i + 1], 0.0f);
        pk[i] = __floats2half2_rn(rx, ry);
    }
    out4[(size_t)node * 8 + l] = *(const float4*)pk;
}

// ---------------- agg32: 4-lane group per node -> fp32 out ----------------

__global__ __launch_bounds__(256) void agg32_kernel(
    const float4* __restrict__ hrow4, const int* __restrict__ ssrc,
    const int* __restrict__ offs, const int* __restrict__ counts,
    const float* __restrict__ dinv, const float* __restrict__ b2,
    float4* __restrict__ out4, int N) {
    int tid  = threadIdx.x;
    int lane = tid & 63;
    int l    = tid & 3;            // lane within group
    int gb   = lane & 60;          // group base lane within wave
    int node = blockIdx.x * 64 + (tid >> 2);
    if (node >= N) return;
    int beg = offs[node], cnt = counts[node];
    float a[8];
#pragma unroll
    for (int j = 0; j < 8; ++j) a[j] = 0.f;
    for (int base = 0; base < cnt; base += 4) {
        int p = base + l;
        int idx = 0;
        float dv = 0.0f;
        if (p < cnt) {
            idx = ssrc[beg + p];
            dv  = dinv[idx];
        }
#pragma unroll
        for (int j = 0; j < 4; ++j) {
            int   s  = __shfl(idx, gb | j, 64);
            float nv = __shfl(dv, gb | j, 64);
            float4 raw = hrow4[(size_t)s * 4 + l];
            float f[8];
            unpack8(raw, f);
#pragma unroll
            for (int d = 0; d < 8; ++d) a[d] = fmaf(f[d], nv, a[d]);
        }
    }
    float dd = dinv[node];
    float4 sraw = hrow4[(size_t)node * 4 + l];
    float sf[8];
    unpack8(sraw, sf);
    float r[8];
#pragma unroll
    for (int j = 0; j < 8; ++j)
        r[j] = dd * (a[j] + sf[j] * dd) + b2[8 * l + j];
    out4[(size_t)node * 8 + 2 * l + 0] = make_float4(r[0], r[1], r[2], r[3]);
    out4[(size_t)node * 8 + 2 * l + 1] = make_float4(r[4], r[5], r[6], r[7]);
}

// ---------------- launch ----------------

extern "C" void kernel_launch(void* const* d_in, const int* in_sizes, int n_in,
                              void* d_out, int out_size, void* d_ws, size_t ws_size,
                              hipStream_t stream) {
    const float* x  = (const float*)d_in[0];
    const int*   ei = (const int*)d_in[1];
    const float* W1 = (const float*)d_in[2];
    const float* b1 = (const float*)d_in[3];
    const float* W2 = (const float*)d_in[4];
    const float* b2 = (const float*)d_in[5];
    float* out = (float*)d_out;

    const int N = in_sizes[0] / 64;   // 100000
    const int E = in_sizes[1] / 2;    // 1200000
    const int* src = ei;
    const int* dst = ei + E;

    const int Npad  = (N + 1023) & ~1023;      // 100352
    const int R     = (N + NBUCK - 1) / NBUCK; // 196 (<= 256)
    const int HB    = (E + CH - 1) / CH;       // 293 (<= 512)
    const int HBpad = (HB + 15) & ~15;         // 304
    const int GB    = 782;

    // workspace layout
    unsigned long long* pairs = (unsigned long long*)d_ws;        // E
    int*   ssrc        = (int*)(pairs + E);                       // E
    int*   counts      = ssrc + E;                                // Npad
    int*   offs        = counts + Npad;                           // Npad
    float* dinv        = (float*)(offs + Npad);                   // Npad
    int*   bucketStart = (int*)(dinv + Npad);                     // NBUCK+1
    int*   totals      = bucketStart + NBUCK + 1;                 // NBUCK (+1 pad)
    int*   blockHist   = totals + NBUCK + 1;                      // HB*NBUCK
    int*   baseTblT    = blockHist + (size_t)HB * NBUCK;          // NBUCK*HBpad
    size_t hoff = (size_t)(baseTblT + (size_t)NBUCK * HBpad - (int*)d_ws);
    hoff = (hoff + 3) & ~(size_t)3;                               // 16B align
    __half* h    = (__half*)((int*)d_ws + hoff);                  // N*64 fp16
    __half* out1 = h + (size_t)N * 64;                            // N*64 fp16
    __half* h2   = h;                                             // N*32 fp16, reuses h

    const int ntiles = (N + 15) / 16;  // 6250

    // K1: dst block-histogram + layer-1 GEMM (independent, fused dispatch)
    hist_gemm1_kernel<<<HB + GB, 256, 0, stream>>>(dst, blockHist, x, W1, h, N, ntiles,
                                                   E, R, HB, GB);
    // K2a: per-bucket column scans (parallel over 512 blocks)
    scan_cols_kernel<<<NBUCK, 256, 0, stream>>>(blockHist, baseTblT, totals, HB, HBpad);
    // K2b: scan bucket totals
    scan_totals_kernel<<<1, NBUCK, 0, stream>>>(totals, bucketStart);
    // K3: single-pass scatter into bucket regions
    scatter_kernel<<<HB, 256, 0, stream>>>(src, dst, baseTblT, bucketStart, pairs, E, R, HBpad);
    // K4: per-bucket CSR build (LDS-staged)
    bucket_csr_kernel<<<NBUCK, 256, 0, stream>>>(pairs, bucketStart, counts, offs, dinv, ssrc,
                                                 N, R);
    // K5: layer-1 aggregation + relu
    agg64_kernel<<<(N + 31) / 32, 256, 0, stream>>>((const float4*)h, ssrc, offs, counts, dinv,
                                                    b1, (float4*)out1, N);
    // K6: layer-2 GEMM
    gemm2_mfma_kernel<<<782, 256, 0, stream>>>(out1, W2, h2, N, ntiles);
    // K7: layer-2 aggregation -> out
    agg32_kernel<<<(N + 63) / 64, 256, 0, stream>>>((const float4*)h2, ssrc, offs, counts, dinv,
                                                    b2, (float4*)out, N);
}